// Round 1
// 165.087 us; speedup vs baseline: 1.0133x; 1.0133x over previous
//
#include <hip/hip_runtime.h>

#define L_LEN 32768
#define QMAXF 127.0f
#define TPB 4   // conv tiles (of 64 t) per block

typedef __attribute__((ext_vector_type(4))) int v4i;

// wsf layout (floats): [0..1536) : phase-1 partials [ic][b][k]  (64*8*3)

// ---------------- pass 1: per-(ic,b) abs-max partials ----------------
// 1024 threads/block -> 16 waves/block, 512 blocks -> 32 waves/CU (full occupancy).
__global__ __launch_bounds__(1024) void actamax_kernel(const float* __restrict__ x,
                                                       float* __restrict__ wsf) {
    const int ic = blockIdx.x, b = blockIdx.y;
    const float4* row = (const float4*)(x + ((size_t)(b*64 + ic) << 15));
    float mA = 0.0f, mNF = 0.0f, mNL = 0.0f;   // all, no-first(t>0), no-last(t<L-1)
    #pragma unroll
    for (int i = 0; i < 8; ++i) {
        int f = threadIdx.x + (i << 10);
        float4 v = row[f];
        float ax = fabsf(v.x), ay = fabsf(v.y), az = fabsf(v.z), aw = fabsf(v.w);
        float m4 = fmaxf(fmaxf(ax, ay), fmaxf(az, aw));
        mA = fmaxf(mA, m4);
        if (f == 0) {
            mNF = fmaxf(mNF, fmaxf(ay, fmaxf(az, aw)));
            mNL = fmaxf(mNL, m4);
        } else if (f == 8191) {
            mNF = fmaxf(mNF, m4);
            mNL = fmaxf(mNL, fmaxf(ax, fmaxf(ay, az)));
        } else {
            mNF = fmaxf(mNF, m4);
            mNL = fmaxf(mNL, m4);
        }
    }
    #pragma unroll
    for (int off = 32; off; off >>= 1) {
        mA  = fmaxf(mA,  __shfl_down(mA,  off));
        mNF = fmaxf(mNF, __shfl_down(mNF, off));
        mNL = fmaxf(mNL, __shfl_down(mNL, off));
    }
    __shared__ float red[3][16];
    int wid = threadIdx.x >> 6;
    if ((threadIdx.x & 63) == 0) { red[0][wid] = mA; red[1][wid] = mNF; red[2][wid] = mNL; }
    __syncthreads();
    if (threadIdx.x == 0) {
        mA = red[0][0]; mNF = red[1][0]; mNL = red[2][0];
        #pragma unroll
        for (int i = 1; i < 16; ++i) {
            mA  = fmaxf(mA,  red[0][i]);
            mNF = fmaxf(mNF, red[1][i]);
            mNL = fmaxf(mNL, red[2][i]);
        }
        // k=0 uses x[-1..L-2] -> exclude last; k=1 all; k=2 uses x[1..L] -> exclude first
        float* p = wsf + (ic*8 + b)*3;
        p[0] = mNL; p[1] = mA; p[2] = mNF;
    }
}

// ---------------- pass 2: fused (redundant prep) + conv MFMA ----------------
// Every block redundantly computes the scales (deterministic, identical in all
// blocks: 6 KB partials + 48 KB weights, L2-hot) -> no serial single-block
// kernel, no wsa round-trip. Then grid-strides TPB conv tiles of 64 t each.
__global__ __launch_bounds__(256) void fused_conv_kernel(const float* __restrict__ x,
                                                         const float* __restrict__ w,
                                                         const float* __restrict__ bias,
                                                         const float* __restrict__ wsf,
                                                         float* __restrict__ out) {
    __shared__ int   bsm[3072];     // A-frag staging, then per-tile B fragments
    __shared__ float scl[192];
    __shared__ float red[256];
    __shared__ float bias_s[64];

    const int tid  = threadIdx.x;
    const int b    = blockIdx.y;
    const int lane = tid & 63;
    const int wv   = tid >> 6;

    // ---- redundant prep: scales ----
    float ax = 0.0f, aww = 0.0f;
    if (tid < 192) {
        float wsc = 0.0f;
        #pragma unroll 8
        for (int o = 0; o < 64; ++o) wsc = fmaxf(wsc, fabsf(w[o*192 + tid]));
        int ic = tid / 3, k = tid - ic*3;
        float asc = 0.0f;
        #pragma unroll
        for (int bb = 0; bb < 8; ++bb) asc = fmaxf(asc, wsf[(ic*8 + bb)*3 + k]);
        float sc = sqrtf(asc) / sqrtf(wsc);    // act**0.5 / w**0.5
        if (sc == 0.0f) sc = 1.0f;
        scl[tid] = sc;
        ax  = asc / sc;     // column max of |cols/scale|
        aww = wsc * sc;     // max |w*scale|
    }
    if (tid < 64) bias_s[tid] = bias[tid];
    red[tid] = ax; __syncthreads();
    for (int s = 128; s; s >>= 1) { if (tid < s) red[tid] = fmaxf(red[tid], red[tid+s]); __syncthreads(); }
    float axm = red[0]; __syncthreads();
    red[tid] = aww; __syncthreads();
    for (int s = 128; s; s >>= 1) { if (tid < s) red[tid] = fmaxf(red[tid], red[tid+s]); __syncthreads(); }
    float awm = red[0];
    const float s_x = (axm == 0.0f) ? 1.0f : axm / QMAXF;
    const float s_w = (awm == 0.0f) ? 1.0f : awm / QMAXF;
    const float sxw = s_x * s_w;

    // ---- quantize weights into MFMA A-fragment order (staged via LDS) ----
    for (int idx = tid; idx < 3072; idx += 256) {
        int oc = idx / 48, dwi = idx - oc*48, j0 = dwi*4;
        unsigned pk = 0;
        #pragma unroll
        for (int bb = 0; bb < 4; ++bb) {
            int j = j0 + bb;
            float q = rintf((w[oc*192 + j] * scl[j]) / s_w);  // ref op order
            q = fminf(fmaxf(q, -QMAXF), QMAXF);
            pk |= (((unsigned)(int)q) & 255u) << (8*bb);
        }
        int mt = oc >> 4, m = oc & 15, c = j0 >> 4, s = c >> 2, kq = c & 3;
        bsm[((mt*3 + s)*64 + kq*16 + m)*4 + ((j0 & 15) >> 2)] = (int)pk;
    }
    __syncthreads();
    v4i afrag[12];
    const v4i* bsmv = (const v4i*)bsm;
    #pragma unroll
    for (int i = 0; i < 12; ++i) afrag[i] = bsmv[i*64 + lane];
    // NOTE: first __syncthreads() inside the tile loop drains each wave's own
    // afrag ds_reads (compiler emits lgkmcnt(0) before s_barrier) before any
    // wave re-writes bsm -> safe reuse.

    // ---- per-thread staging roles ----
    const int tq  = tid & 15;      // owns t = 4*tq .. 4*tq+3 (tile-local)
    const int icg = tid >> 4;      // owns ic = 4*icg .. 4*icg+3
    const int tb  = tq << 2;

    float rv[12];
    #pragma unroll
    for (int jj = 0; jj < 12; ++jj) rv[jj] = 1.0f / (scl[icg*12 + jj] * s_x);

    // ---- conv tiles: pipeline loads of tile i+1 under MFMA/epilogue of i ----
    float xv[4][6];                // [ici][t-1 .. t+4]
    {
        const int t0 = (blockIdx.x * TPB) << 6;
        #pragma unroll
        for (int ici = 0; ici < 4; ++ici) {
            const float* rowp = x + (((size_t)(b*64 + icg*4 + ici)) << 15) + t0 + tb;
            float4 mid = *(const float4*)rowp;
            float lm = (t0 + tb > 0)           ? rowp[-1] : 0.0f;
            float rp = (t0 + tb + 4 < L_LEN)   ? rowp[4]  : 0.0f;
            xv[ici][0] = lm;    xv[ici][1] = mid.x; xv[ici][2] = mid.y;
            xv[ici][3] = mid.z; xv[ici][4] = mid.w; xv[ici][5] = rp;
        }
    }

    for (int it = 0; it < TPB; ++it) {
        const int t0c = (blockIdx.x * TPB + it) << 6;

        // quantize current tile from xv into registers (consumes xv)
        unsigned pkq[12];
        #pragma unroll
        for (int dt = 0; dt < 4; ++dt) {
            #pragma unroll
            for (int dw = 0; dw < 3; ++dw) {
                unsigned pk = 0;
                #pragma unroll
                for (int bb = 0; bb < 4; ++bb) {
                    int jloc = dw*4 + bb;           // j = 12*icg + jloc = 3*ic + k
                    int ici = jloc / 3, k = jloc - ici*3;
                    float q = rintf(xv[ici][dt + k] * rv[jloc]);
                    q = fminf(fmaxf(q, -QMAXF), QMAXF);
                    pk |= (((unsigned)(int)q) & 255u) << (8*bb);
                }
                pkq[dt*3 + dw] = pk;
            }
        }

        __syncthreads();   // prev tile's ds_reads done -> bsm free
        #pragma unroll
        for (int dt = 0; dt < 4; ++dt) {
            int t = tb + dt, wt = t >> 4, n = t & 15;
            #pragma unroll
            for (int dw = 0; dw < 3; ++dw) {
                int j0 = icg*12 + dw*4;
                int c = j0 >> 4, s = c >> 2, kq = c & 3;
                bsm[((wt*3 + s)*64 + kq*16 + n)*4 + ((j0 & 15) >> 2)] = (int)pkq[dt*3 + dw];
            }
        }
        __syncthreads();

        // prefetch next tile's x (in flight across MFMA + epilogue)
        if (it + 1 < TPB) {
            const int t0n = (blockIdx.x * TPB + it + 1) << 6;
            #pragma unroll
            for (int ici = 0; ici < 4; ++ici) {
                const float* rowp = x + (((size_t)(b*64 + icg*4 + ici)) << 15) + t0n + tb;
                float4 mid = *(const float4*)rowp;
                float lm = (t0n + tb > 0)          ? rowp[-1] : 0.0f;
                float rp = (t0n + tb + 4 < L_LEN)  ? rowp[4]  : 0.0f;
                xv[ici][0] = lm;    xv[ici][1] = mid.x; xv[ici][2] = mid.y;
                xv[ici][3] = mid.z; xv[ici][4] = mid.w; xv[ici][5] = rp;
            }
        }

        // ---- MFMA ----
        v4i acc[4];
        #pragma unroll
        for (int mt = 0; mt < 4; ++mt) acc[mt] = (v4i){0,0,0,0};
        const v4i* bsmv2 = (const v4i*)bsm;
        #pragma unroll
        for (int s = 0; s < 3; ++s) {
            v4i bf = bsmv2[(wv*3 + s)*64 + lane];
            #pragma unroll
            for (int mt = 0; mt < 4; ++mt)
                acc[mt] = __builtin_amdgcn_mfma_i32_16x16x64_i8(afrag[mt*3 + s], bf, acc[mt], 0, 0, 0);
        }

        // ---- epilogue: col=lane&15 -> t, row=(lane>>4)*4+i -> oc ----
        const int tg   = t0c + (wv << 4) + (lane & 15);
        const int rowq = (lane >> 4) << 2;
        #pragma unroll
        for (int mt = 0; mt < 4; ++mt) {
            #pragma unroll
            for (int i = 0; i < 4; ++i) {
                int oc = mt*16 + rowq + i;
                out[(((size_t)(b*64 + oc)) << 15) + tg] = (float)acc[mt][i] * sxw + bias_s[oc];
            }
        }
    }
}

extern "C" void kernel_launch(void* const* d_in, const int* in_sizes, int n_in,
                              void* d_out, int out_size, void* d_ws, size_t ws_size,
                              hipStream_t stream) {
    const float* x    = (const float*)d_in[0];
    const float* w    = (const float*)d_in[1];
    const float* bias = (const float*)d_in[2];
    float* out = (float*)d_out;
    float* wsf = (float*)d_ws;

    hipLaunchKernelGGL(actamax_kernel,   dim3(64, 8),  dim3(1024), 0, stream, x, wsf);
    hipLaunchKernelGGL(fused_conv_kernel, dim3(512 / TPB, 8), dim3(256), 0, stream,
                       x, w, bias, wsf, out);
}

// Round 2
// 150.478 us; speedup vs baseline: 1.1117x; 1.0971x over previous
//
#include <hip/hip_runtime.h>

#define L_LEN 32768
#define QMAXF 127.0f
#define TPB 4   // conv tiles (of 64 t) per block

typedef __attribute__((ext_vector_type(4))) int v4i;

// wsf layout (floats):
//   [0..1536)    : phase-1 partials [ic][b][k]  (64*8*3)
//   [1536..1728) : rv_j = 1/(scale_j * s_x)
//   [1728]       : s_x * s_w
// wsa (byte offset 8192): A fragments (quantized weights, i8, MFMA lane-chunk order)

// ---------------- pass 1: per-(ic,b) abs-max partials ----------------
// 1024 threads/block, 512 blocks -> full-occupancy BW-bound reduction.
__global__ __launch_bounds__(1024) void actamax_kernel(const float* __restrict__ x,
                                                       float* __restrict__ wsf) {
    const int ic = blockIdx.x, b = blockIdx.y;
    const float4* row = (const float4*)(x + ((size_t)(b*64 + ic) << 15));
    float mA = 0.0f, mNF = 0.0f, mNL = 0.0f;   // all, no-first(t>0), no-last(t<L-1)
    #pragma unroll
    for (int i = 0; i < 8; ++i) {
        int f = threadIdx.x + (i << 10);
        float4 v = row[f];
        float ax = fabsf(v.x), ay = fabsf(v.y), az = fabsf(v.z), aw = fabsf(v.w);
        float m4 = fmaxf(fmaxf(ax, ay), fmaxf(az, aw));
        mA = fmaxf(mA, m4);
        if (f == 0) {
            mNF = fmaxf(mNF, fmaxf(ay, fmaxf(az, aw)));
            mNL = fmaxf(mNL, m4);
        } else if (f == 8191) {
            mNF = fmaxf(mNF, m4);
            mNL = fmaxf(mNL, fmaxf(ax, fmaxf(ay, az)));
        } else {
            mNF = fmaxf(mNF, m4);
            mNL = fmaxf(mNL, m4);
        }
    }
    #pragma unroll
    for (int off = 32; off; off >>= 1) {
        mA  = fmaxf(mA,  __shfl_down(mA,  off));
        mNF = fmaxf(mNF, __shfl_down(mNF, off));
        mNL = fmaxf(mNL, __shfl_down(mNL, off));
    }
    __shared__ float red[3][16];
    int wid = threadIdx.x >> 6;
    if ((threadIdx.x & 63) == 0) { red[0][wid] = mA; red[1][wid] = mNF; red[2][wid] = mNL; }
    __syncthreads();
    if (threadIdx.x == 0) {
        mA = red[0][0]; mNF = red[1][0]; mNL = red[2][0];
        #pragma unroll
        for (int i = 1; i < 16; ++i) {
            mA  = fmaxf(mA,  red[0][i]);
            mNF = fmaxf(mNF, red[1][i]);
            mNL = fmaxf(mNL, red[2][i]);
        }
        // k=0 uses x[-1..L-2] -> exclude last; k=1 all; k=2 uses x[1..L] -> exclude first
        float* p = wsf + (ic*8 + b)*3;
        p[0] = mNL; p[1] = mA; p[2] = mNF;
    }
}

// ---------------- pass 2: one tiny block computes scales + quantized A ----------------
__global__ __launch_bounds__(256) void prep_kernel(const float* __restrict__ w,
                                                   float* __restrict__ wsf,
                                                   unsigned int* __restrict__ wsa) {
    __shared__ float scl[192];
    __shared__ float red[256];
    const int tid = threadIdx.x;
    float ax = 0.0f, aw = 0.0f;
    if (tid < 192) {
        float wsc = 0.0f;
        #pragma unroll 8
        for (int o = 0; o < 64; ++o) wsc = fmaxf(wsc, fabsf(w[o*192 + tid]));
        int ic = tid / 3, k = tid - ic*3;
        float asc = 0.0f;
        #pragma unroll
        for (int b = 0; b < 8; ++b) asc = fmaxf(asc, wsf[(ic*8 + b)*3 + k]);
        float sc = sqrtf(asc) / sqrtf(wsc);    // act**0.5 / w**0.5
        if (sc == 0.0f) sc = 1.0f;
        scl[tid] = sc;
        ax = asc / sc;     // column max of |cols/scale| (monotone fp div)
        aw = wsc * sc;     // max |w*scale|
    }
    red[tid] = ax; __syncthreads();
    for (int s = 128; s; s >>= 1) { if (tid < s) red[tid] = fmaxf(red[tid], red[tid+s]); __syncthreads(); }
    float axm = red[0]; __syncthreads();
    red[tid] = aw; __syncthreads();
    for (int s = 128; s; s >>= 1) { if (tid < s) red[tid] = fmaxf(red[tid], red[tid+s]); __syncthreads(); }
    float awm = red[0];
    float s_x = (axm == 0.0f) ? 1.0f : axm / QMAXF;
    float s_w = (awm == 0.0f) ? 1.0f : awm / QMAXF;
    if (tid < 192) wsf[1536 + tid] = 1.0f / (scl[tid] * s_x);
    if (tid == 0)  wsf[1728] = s_x * s_w;
    __syncthreads();
    // quantize weights into MFMA A-fragment (16x16x64 i8) lane-chunk order
    for (int idx = tid; idx < 3072; idx += 256) {
        int oc = idx / 48, dwi = idx - oc*48, j0 = dwi*4;
        unsigned pk = 0;
        #pragma unroll
        for (int bb = 0; bb < 4; ++bb) {
            int j = j0 + bb;
            float q = rintf((w[oc*192 + j] * scl[j]) / s_w);  // ref op order
            q = fminf(fmaxf(q, -QMAXF), QMAXF);
            pk |= (((unsigned)(int)q) & 255u) << (8*bb);
        }
        int mt = oc >> 4, m = oc & 15, c = j0 >> 4, s = c >> 2, kq = c & 3;
        wsa[((mt*3 + s)*64 + kq*16 + m)*4 + ((j0 & 15) >> 2)] = pk;
    }
}

// ---------------- pass 3: conv as i8 MFMA GEMM ----------------
// D[oc][t] = sum_j qw[oc][j] * qx[j][t], j = ic*3+k.
// Block: TPB tiles of 64 t x 64 oc x 1 batch; 4 waves, wave w owns t-range [16w,16w+16).
// LDS B-staging uses granule XOR swizzle G^=(G>>6)&7 on BOTH sides:
//   write banks become 32x2-way (free, m136); read stays a permutation
//   within 8-lane groups of a consecutive ds_read_b128 (conflict-free).
__global__ __launch_bounds__(256) void conv_mfma_kernel(const float* __restrict__ x,
                                                        const float* __restrict__ bias,
                                                        const float* __restrict__ wsf,
                                                        const v4i* __restrict__ wsa,
                                                        float* __restrict__ out) {
    __shared__ int bsm[3072];   // B fragments (swizzled granules)
    const int tid  = threadIdx.x;
    const int b    = blockIdx.y;
    const int lane = tid & 63;
    const int wv   = tid >> 6;

    // per-thread staging roles
    const int tq  = tid & 15;      // owns t = 4*tq .. 4*tq+3 (tile-local)
    const int icg = tid >> 4;      // owns ic = 4*icg .. 4*icg+3  (j = 12*icg..+11)
    const int tb  = tq << 2;

    // first tile's x loads issued first (longest latency)
    float xv[4][6];                // [ici][t-1 .. t+4]
    {
        const int t0 = (blockIdx.x * TPB) << 6;
        #pragma unroll
        for (int ici = 0; ici < 4; ++ici) {
            const float* rowp = x + (((size_t)(b*64 + icg*4 + ici)) << 15) + t0 + tb;
            float4 mid = *(const float4*)rowp;
            float lm = (t0 + tb > 0)           ? rowp[-1] : 0.0f;
            float rp = (t0 + tb + 4 < L_LEN)   ? rowp[4]  : 0.0f;
            xv[ici][0] = lm;    xv[ici][1] = mid.x; xv[ici][2] = mid.y;
            xv[ici][3] = mid.z; xv[ici][4] = mid.w; xv[ici][5] = rp;
        }
    }

    // A fragments: 4 m-tiles x 3 k-steps (L2-hot)
    v4i afrag[12];
    #pragma unroll
    for (int i = 0; i < 12; ++i) afrag[i] = wsa[i*64 + lane];

    float rv[12];
    #pragma unroll
    for (int jj = 0; jj < 12; ++jj) rv[jj] = wsf[1536 + icg*12 + jj];
    const float sxw = wsf[1728];

    for (int it = 0; it < TPB; ++it) {
        const int t0c = (blockIdx.x * TPB + it) << 6;

        // quantize current tile from xv into registers (consumes xv)
        unsigned pkq[12];
        #pragma unroll
        for (int dt = 0; dt < 4; ++dt) {
            #pragma unroll
            for (int dw = 0; dw < 3; ++dw) {
                unsigned pk = 0;
                #pragma unroll
                for (int bb = 0; bb < 4; ++bb) {
                    int jloc = dw*4 + bb;           // j = 12*icg + jloc = 3*ic + k
                    int ici = jloc / 3, k = jloc - ici*3;
                    float q = rintf(xv[ici][dt + k] * rv[jloc]);
                    q = fminf(fmaxf(q, -QMAXF), QMAXF);
                    pk |= (((unsigned)(int)q) & 255u) << (8*bb);
                }
                pkq[dt*3 + dw] = pk;
            }
        }

        if (it) __syncthreads();   // prev tile's ds_reads done -> bsm free
        #pragma unroll
        for (int dt = 0; dt < 4; ++dt) {
            int t = tb + dt, wt = t >> 4, n = t & 15;
            #pragma unroll
            for (int dw = 0; dw < 3; ++dw) {
                int j0 = icg*12 + dw*4;
                int c = j0 >> 4, s = c >> 2, kq = c & 3;
                int G = (wt*3 + s)*64 + kq*16 + n;
                G ^= (G >> 6) & 7;                 // bank swizzle
                bsm[G*4 + ((j0 & 15) >> 2)] = (int)pkq[dt*3 + dw];
            }
        }
        __syncthreads();

        // prefetch next tile's x (in flight across MFMA + epilogue)
        if (it + 1 < TPB) {
            const int t0n = (blockIdx.x * TPB + it + 1) << 6;
            #pragma unroll
            for (int ici = 0; ici < 4; ++ici) {
                const float* rowp = x + (((size_t)(b*64 + icg*4 + ici)) << 15) + t0n + tb;
                float4 mid = *(const float4*)rowp;
                float lm = (t0n + tb > 0)          ? rowp[-1] : 0.0f;
                float rp = (t0n + tb + 4 < L_LEN)  ? rowp[4]  : 0.0f;
                xv[ici][0] = lm;    xv[ici][1] = mid.x; xv[ici][2] = mid.y;
                xv[ici][3] = mid.z; xv[ici][4] = mid.w; xv[ici][5] = rp;
            }
        }

        // ---- MFMA ----
        v4i acc[4];
        #pragma unroll
        for (int mt = 0; mt < 4; ++mt) acc[mt] = (v4i){0,0,0,0};
        const v4i* bsmv = (const v4i*)bsm;
        #pragma unroll
        for (int s = 0; s < 3; ++s) {
            int Gr = (wv*3 + s)*64 + lane;
            Gr ^= (wv*3 + s) & 7;                  // same swizzle ((Gr>>6)&7)
            v4i bf = bsmv[Gr];
            #pragma unroll
            for (int mt = 0; mt < 4; ++mt)
                acc[mt] = __builtin_amdgcn_mfma_i32_16x16x64_i8(afrag[mt*3 + s], bf, acc[mt], 0, 0, 0);
        }

        // ---- epilogue: C/D layout col=lane&15 -> t, row=(lane>>4)*4+i -> oc ----
        const int tg   = t0c + (wv << 4) + (lane & 15);
        const int rowq = (lane >> 4) << 2;
        #pragma unroll
        for (int mt = 0; mt < 4; ++mt) {
            #pragma unroll
            for (int i = 0; i < 4; ++i) {
                int oc = mt*16 + rowq + i;
                out[(((size_t)(b*64 + oc)) << 15) + tg] = (float)acc[mt][i] * sxw + bias[oc];
            }
        }
    }
}

extern "C" void kernel_launch(void* const* d_in, const int* in_sizes, int n_in,
                              void* d_out, int out_size, void* d_ws, size_t ws_size,
                              hipStream_t stream) {
    const float* x    = (const float*)d_in[0];
    const float* w    = (const float*)d_in[1];
    const float* bias = (const float*)d_in[2];
    float* out = (float*)d_out;
    float* wsf = (float*)d_ws;
    unsigned int* wsa = (unsigned int*)((char*)d_ws + 8192);

    hipLaunchKernelGGL(actamax_kernel,   dim3(64, 8),       dim3(1024), 0, stream, x, wsf);
    hipLaunchKernelGGL(prep_kernel,      dim3(1),           dim3(256),  0, stream, w, wsf, wsa);
    hipLaunchKernelGGL(conv_mfma_kernel, dim3(512/TPB, 8),  dim3(256),  0, stream,
                       x, bias, wsf, (const v4i*)wsa, out);
}